// Round 2
// baseline (368.708 us; speedup 1.0000x reference)
//
#include <hip/hip_runtime.h>

// Problem constants
#define B_   8
#define T1_  4
#define TP_  3
#define TF_  4
#define C_   256
#define HW_  4096

// Workspace layout (bytes)
#define OFF_FP     0ull          // feature_p bf16: 8*4*256*4096*2 = 67108864
#define OFF_PMAXK  67108864ull   // fp pool max keys (uint) B*TP*C = 24576 B
#define OFF_PSUM   67133440ull   // fp pool sums (float)              24576 B
#define OFF_RMAX   67158016ull   // raw pool max (float) B*C           8192 B
#define OFF_RSUM   67166208ull   // raw pool sum (float)               8192 B
#define OFF_Q      67174400ull   // q: B*TF*C floats                  32768 B
#define OFF_K      67207168ull   // k: B*TP*C floats                  24576 B
#define OFF_AW     67231744ull   // attn_w: B*TF*TP floats              384 B
#define OFF_WFRAG  67232128ull   // W bf16 fragment-order: 65536*2 = 131072 B
#define WS_NEED    67363200ull

typedef __attribute__((ext_vector_type(8))) short bf16x8;
typedef __attribute__((ext_vector_type(4))) float f32x4;

__device__ __forceinline__ unsigned short f2bf(float f) {
    unsigned int u = __float_as_uint(f);
    u += 0x7fffu + ((u >> 16) & 1u);        // RNE
    return (unsigned short)(u >> 16);
}
__device__ __forceinline__ unsigned int cvtpk(float lo, float hi) {
    // D[15:0]=bf16(lo), D[31:16]=bf16(hi), RNE — same bits as f2bf pair
    unsigned int r;
    asm("v_cvt_pk_bf16_f32 %0, %1, %2" : "=v"(r) : "v"(lo), "v"(hi));
    return r;
}
__device__ __forceinline__ unsigned int fkey(float x) {
    unsigned int b = __float_as_uint(x);
    return (b & 0x80000000u) ? ~b : (b | 0x80000000u);
}
__device__ __forceinline__ float funkey(unsigned int k) {
    unsigned int b = (k & 0x80000000u) ? (k ^ 0x80000000u) : ~k;
    return __uint_as_float(b);
}
__device__ __forceinline__ float silu_f(float x) { return x / (1.0f + __expf(-x)); }

__device__ __forceinline__ void dec8(uint4 u, float* f) {
    f[0] = __uint_as_float(u.x << 16); f[1] = __uint_as_float(u.x & 0xffff0000u);
    f[2] = __uint_as_float(u.y << 16); f[3] = __uint_as_float(u.y & 0xffff0000u);
    f[4] = __uint_as_float(u.z << 16); f[5] = __uint_as_float(u.z & 0xffff0000u);
    f[6] = __uint_as_float(u.w << 16); f[7] = __uint_as_float(u.w & 0xffff0000u);
}

// ---------------- k_wpre: W fp32 -> bf16 in MFMA A-fragment order ------------
// Fragment-linear layout: 16B frag index fi = (s*16 + ob)*64 + (q*16 + col),
// element j of that frag = W[ob*16 + col][32*s + 8*q + j].
__global__ __launch_bounds__(256) void k_wpre(const float* __restrict__ Wc,
                                              unsigned short* __restrict__ wfrag) {
    const int idx = blockIdx.x * 256 + threadIdx.x;   // 0..65535 (coalesced writes)
    const int j   = idx & 7;
    const int fi  = idx >> 3;
    const int col = fi & 15;
    const int q   = (fi >> 4) & 3;
    const int sob = fi >> 6;
    const int ob  = sob & 15;
    const int s   = sob >> 4;
    const int o   = ob * 16 + col;
    const int c   = s * 32 + q * 8 + j;
    wfrag[idx] = f2bf(Wc[o * 256 + c]);
}

// ---------------- K0: pool raw feature[:, 3] over HW (max & sum per (b,c)) ----
__global__ __launch_bounds__(256) void k0_rawpool(const float* __restrict__ feature,
                                                  float* __restrict__ rmax,
                                                  float* __restrict__ rsum) {
    const int blk = blockIdx.x;           // 2048 = B * C
    const int b = blk >> 8, c = blk & 255;
    const float* base = feature + ((size_t)(b * 4 + 3) * C_ + c) * HW_;
    const int tid = threadIdx.x;
    float mx = -3.4e38f, sm = 0.0f;
    #pragma unroll
    for (int k = 0; k < 4; ++k) {
        float4 v = *(const float4*)(base + (k * 256 + tid) * 4);
        mx = fmaxf(mx, fmaxf(fmaxf(v.x, v.y), fmaxf(v.z, v.w)));
        sm += (v.x + v.y) + (v.z + v.w);
    }
    #pragma unroll
    for (int m = 1; m < 64; m <<= 1) {
        mx = fmaxf(mx, __shfl_xor(mx, m));
        sm += __shfl_xor(sm, m);
    }
    __shared__ float wmx[4], wsm[4];
    const int wave = tid >> 6;
    if ((tid & 63) == 0) { wmx[wave] = mx; wsm[wave] = sm; }
    __syncthreads();
    if (tid == 0) {
        rmax[b * C_ + c] = fmaxf(fmaxf(wmx[0], wmx[1]), fmaxf(wmx[2], wmx[3]));
        rsum[b * C_ + c] = (wsm[0] + wsm[1]) + (wsm[2] + wsm[3]);
    }
}

// ---------------- K1: conv(1x1) + BN + silu -> feature_p (bf16) + fp pooling ---
// Block: 256 threads (4 waves), tile 256o x 64hw for one (b,t). BK=32, 8 steps.
// NO LDS tiles, NO barriers in the K-loop: A frags come straight from global
// wfrag (bf16, fragment order, L2-hot); B frags come straight from global
// feature as 8 scalar fp32 loads per frag (lane(q,col) needs
// F[k0+q*8+j][hw0+ni*16+col] — exactly the mfma B layout) + 4 cvt_pk each.
// B is re-read by all 4 waves (L2 absorbs it); in exchange every wave is an
// independent, deeply-pipelined load/MFMA stream with zero inter-wave sync.
__global__ __launch_bounds__(256, 2) void k1_conv(
    const float* __restrict__ feature, const unsigned short* __restrict__ wfrag,
    const float* __restrict__ gamma, const float* __restrict__ beta,
    const float* __restrict__ mean, const float* __restrict__ var,
    unsigned short* __restrict__ fp_out,
    unsigned int* __restrict__ pmaxk, float* __restrict__ psum) {
    __shared__ float s_scale[256];
    __shared__ float s_shift[256];

    const int tid   = threadIdx.x;
    const int bt    = blockIdx.x >> 6;       // (b,t) 0..31
    const int hwblk = blockIdx.x & 63;
    const int b = bt >> 2, t = bt & 3;
    const int hw0 = hwblk * 64;
    const int lane = tid & 63;
    const int wave = tid >> 6;               // o-quadrant
    const int q = lane >> 4;
    const int col = lane & 15;

    {
        float sc = gamma[tid] * rsqrtf(var[tid] + 1e-3f);
        s_scale[tid] = sc;
        s_shift[tid] = beta[tid] - mean[tid] * sc;
    }
    __syncthreads();                          // the only barrier in this kernel

    // per-thread B base: row q*8, column hw0+col within this (b,t) slice
    const float* Fq = feature + (size_t)bt * C_ * HW_ + (size_t)(q * 8) * HW_
                      + hw0 + col;
    // per-thread A base: fragment stream for this wave's o-quadrant
    const unsigned short* Wq = wfrag + ((size_t)(wave * 4) * 64 + lane) * 8;

    f32x4 acc[4][4] = {};

    #pragma unroll
    for (int s = 0; s < 8; ++s) {
        bf16x8 afr[4];
        #pragma unroll
        for (int mi = 0; mi < 4; ++mi)
            afr[mi] = *(const bf16x8*)(Wq + (size_t)((s * 16 + mi) * 64) * 8);

        bf16x8 bfr[4];
        #pragma unroll
        for (int ni = 0; ni < 4; ++ni) {
            float fv[8];
            #pragma unroll
            for (int j = 0; j < 8; ++j)
                fv[j] = Fq[(size_t)(s * 32 + j) * HW_ + ni * 16];
            uint4 pk;
            pk.x = cvtpk(fv[0], fv[1]);
            pk.y = cvtpk(fv[2], fv[3]);
            pk.z = cvtpk(fv[4], fv[5]);
            pk.w = cvtpk(fv[6], fv[7]);
            bfr[ni] = __builtin_bit_cast(bf16x8, pk);
        }

        #pragma unroll
        for (int mi = 0; mi < 4; ++mi)
            #pragma unroll
            for (int ni = 0; ni < 4; ++ni)
                acc[mi][ni] = __builtin_amdgcn_mfma_f32_16x16x32_bf16(
                    afr[mi], bfr[ni], acc[mi][ni], 0, 0, 0);
    }

    // epilogue: BN + silu, store bf16; pooling via quarter-wave shuffle reduce
    unsigned short* fpo = fp_out + (size_t)bt * C_ * HW_;
    #pragma unroll
    for (int mi = 0; mi < 4; ++mi) {
        #pragma unroll
        for (int r = 0; r < 4; ++r) {
            const int o = wave * 64 + mi * 16 + q * 4 + r;   // quarter-uniform
            const float sc = s_scale[o], sh = s_shift[o];
            float mx = -3.4e38f, sm = 0.0f;
            #pragma unroll
            for (int ni = 0; ni < 4; ++ni) {
                float x = acc[mi][ni][r] * sc + sh;
                float sl = silu_f(x);
                fpo[(size_t)o * HW_ + hw0 + ni * 16 + col] = f2bf(sl);
                mx = fmaxf(mx, sl);
                sm += sl;
            }
            if (t < 3) {
                #pragma unroll
                for (int m = 1; m < 16; m <<= 1) {   // reduce over col (intra-quarter)
                    mx = fmaxf(mx, __shfl_xor(mx, m));
                    sm += __shfl_xor(sm, m);
                }
                if (col == 0) {
                    atomicMax(&pmaxk[(b * 3 + t) * C_ + o], fkey(mx));
                    atomicAdd(&psum[(b * 3 + t) * C_ + o], sm);
                }
            }
        }
    }
}

// ---------------- K2a: attn_in (p and f sides) -> k / q (all fp32) -------------
__global__ __launch_bounds__(256) void k2_vec(
    const float* __restrict__ past_tc, const float* __restrict__ fut_tc,
    const float* __restrict__ w_tc, const float* __restrict__ b_tc,
    const float* __restrict__ w_in, const float* __restrict__ b_in,
    const float* __restrict__ w_q, const float* __restrict__ b_q,
    const float* __restrict__ w_k, const float* __restrict__ b_k,
    const unsigned int* __restrict__ pmaxk, const float* __restrict__ psum,
    const float* __restrict__ rmax, const float* __restrict__ rsum,
    float* __restrict__ qout, float* __restrict__ kout) {
    __shared__ float pool[512];
    __shared__ float avec[256];
    const int b = blockIdx.x / 7;
    const int idx = blockIdx.x % 7;      // 0..2 = p-side t, 3..6 = f-side f
    const int o = threadIdx.x;
    const bool pside = (idx < 3);
    if (pside) {
        pool[o]       = funkey(pmaxk[(b * 3 + idx) * C_ + o]);
        pool[256 + o] = psum[(b * 3 + idx) * C_ + o] * (1.0f / 4096.0f);
    } else {
        pool[o]       = rmax[b * C_ + o];
        pool[256 + o] = rsum[b * C_ + o] * (1.0f / 4096.0f);
    }
    __syncthreads();
    float s = b_in[o];
    const float* wr = w_in + (size_t)o * 512;
    #pragma unroll 8
    for (int c = 0; c < 512; ++c) s += wr[c] * pool[c];
    float v = silu_f(s);
    float tcin = pside ? past_tc[b * 3 + idx] : fut_tc[b * 4 + (idx - 3)];
    float tc = tanhf(tcin * w_tc[o] + b_tc[o]);
    avec[o] = v + tc;
    __syncthreads();
    if (pside) {
        float s2 = b_k[o];
        const float* wk = w_k + (size_t)o * 256;
        #pragma unroll 8
        for (int c = 0; c < 256; ++c) s2 += wk[c] * avec[c];
        kout[(b * 3 + idx) * C_ + o] = s2;
    } else {
        float s2 = b_q[o];
        const float* wq = w_q + (size_t)o * 256;
        #pragma unroll 8
        for (int c = 0; c < 256; ++c) s2 += wq[c] * avec[c];
        qout[(b * 4 + (idx - 3)) * C_ + o] = s2;
    }
}

// ---------------- K2b: attn_w[b][f][p] = q.k / sqrt(TF) -----------------------
__global__ __launch_bounds__(64) void k2_attnw(const float* __restrict__ qv,
                                               const float* __restrict__ kv,
                                               float* __restrict__ aw) {
    const int i = blockIdx.x;            // 96 = B*TF*TP
    const int b = i / 12, rr = i % 12, f = rr / 3, p = rr % 3;
    const int lane = threadIdx.x;
    const float* qp = qv + (b * 4 + f) * C_;
    const float* kp = kv + (b * 3 + p) * C_;
    float s = 0.0f;
    #pragma unroll
    for (int j = 0; j < 4; ++j) s += qp[lane + 64 * j] * kp[lane + 64 * j];
    #pragma unroll
    for (int m = 1; m < 64; m <<= 1) s += __shfl_xor(s, m);
    if (lane == 0) aw[b * 12 + rr] = s * 0.5f;   // / sqrt(TF=4)
}

// ---------------- K3: out = last + (p_attn/TP) * sum_p aw*(fp3 - fp_p) --------
__global__ __launch_bounds__(256) void k3_out(
    const float* __restrict__ feature, const unsigned short* __restrict__ fp,
    const float* __restrict__ aw, const float* __restrict__ p_attn,
    float* __restrict__ out) {
    const int idx = blockIdx.x;              // 4096 = B * C * 2
    const int b = idx >> 9;
    const int c = (idx >> 1) & 255;
    const int half = idx & 1;
    const int hw = half * 2048 + threadIdx.x * 8;

    float a[12];
    #pragma unroll
    for (int i = 0; i < 12; ++i) a[i] = aw[b * 12 + i];
    const float pa = p_attn[c] * (1.0f / 3.0f);

    const size_t ts = (size_t)C_ * HW_;
    const size_t base = ((size_t)(b * 4) * C_ + c) * HW_ + hw;

    uint4 u0 = *(const uint4*)(fp + base);
    uint4 u1 = *(const uint4*)(fp + base + ts);
    uint4 u2 = *(const uint4*)(fp + base + 2 * ts);
    uint4 u3 = *(const uint4*)(fp + base + 3 * ts);
    float4 l0 = *(const float4*)(feature + base + 3 * ts);
    float4 l1 = *(const float4*)(feature + base + 3 * ts + 4);

    float f0[8], f1[8], f2[8], f3[8];
    dec8(u0, f0); dec8(u1, f1); dec8(u2, f2); dec8(u3, f3);
    float lastv[8] = {l0.x, l0.y, l0.z, l0.w, l1.x, l1.y, l1.z, l1.w};

    float ov[4][8];
    #pragma unroll
    for (int e = 0; e < 8; ++e) {
        float d0 = f3[e] - f0[e];
        float d1 = f3[e] - f1[e];
        float d2 = f3[e] - f2[e];
        #pragma unroll
        for (int f = 0; f < 4; ++f) {
            float at = a[f * 3 + 0] * d0 + a[f * 3 + 1] * d1 + a[f * 3 + 2] * d2;
            ov[f][e] = lastv[e] + at * pa;
        }
    }
    #pragma unroll
    for (int f = 0; f < 4; ++f) {
        size_t ob = ((size_t)(b * 4 + f) * C_ + c) * HW_ + hw;
        *(float4*)(out + ob)     = make_float4(ov[f][0], ov[f][1], ov[f][2], ov[f][3]);
        *(float4*)(out + ob + 4) = make_float4(ov[f][4], ov[f][5], ov[f][6], ov[f][7]);
    }
}

extern "C" void kernel_launch(void* const* d_in, const int* in_sizes, int n_in,
                              void* d_out, int out_size, void* d_ws, size_t ws_size,
                              hipStream_t stream) {
    const float* feature = (const float*)d_in[0];
    const float* past_tc = (const float*)d_in[1];
    const float* fut_tc  = (const float*)d_in[2];
    const float* w_tc    = (const float*)d_in[3];
    const float* b_tc    = (const float*)d_in[4];
    const float* w_in    = (const float*)d_in[5];
    const float* b_in    = (const float*)d_in[6];
    const float* conv_w  = (const float*)d_in[7];
    const float* gamma   = (const float*)d_in[8];
    const float* beta    = (const float*)d_in[9];
    const float* mean    = (const float*)d_in[10];
    const float* var     = (const float*)d_in[11];
    const float* w_q     = (const float*)d_in[12];
    const float* b_q     = (const float*)d_in[13];
    const float* w_k     = (const float*)d_in[14];
    const float* b_k     = (const float*)d_in[15];
    const float* p_attn  = (const float*)d_in[16];

    char* ws = (char*)d_ws;
    unsigned short* fp  = (unsigned short*)(ws + OFF_FP);
    unsigned int* pmaxk = (unsigned int*)(ws + OFF_PMAXK);
    float* psum = (float*)(ws + OFF_PSUM);
    float* rmax = (float*)(ws + OFF_RMAX);
    float* rsum = (float*)(ws + OFF_RSUM);
    float* qout = (float*)(ws + OFF_Q);
    float* kout = (float*)(ws + OFF_K);
    float* aw   = (float*)(ws + OFF_AW);
    // W fragment buffer: workspace if it fits, else scratch in the (not yet
    // written) tail of d_out — k1 finishes reading it before k3 writes out.
    unsigned short* wfrag = (ws_size >= WS_NEED)
        ? (unsigned short*)(ws + OFF_WFRAG)
        : (unsigned short*)((char*)d_out + (size_t)out_size - 131072);

    // zero the fp-pool accumulators (maxkey 0 == below all finite floats; sum 0.0f)
    hipMemsetAsync(ws + OFF_PMAXK, 0, 49152, stream);

    k_wpre<<<256, 256, 0, stream>>>(conv_w, wfrag);
    k0_rawpool<<<B_ * C_, 256, 0, stream>>>(feature, rmax, rsum);
    k1_conv<<<B_ * T1_ * 64, 256, 0, stream>>>(feature, wfrag, gamma, beta, mean, var,
                                               fp, pmaxk, psum);
    k2_vec<<<B_ * 7, 256, 0, stream>>>(past_tc, fut_tc, w_tc, b_tc, w_in, b_in,
                                       w_q, b_q, w_k, b_k, pmaxk, psum, rmax, rsum,
                                       qout, kout);
    k2_attnw<<<B_ * TF_ * TP_, 64, 0, stream>>>(qout, kout, aw);
    k3_out<<<B_ * C_ * 2, 256, 0, stream>>>(feature, fp, aw, p_attn, (float*)d_out);
}

// Round 3
// 354.646 us; speedup vs baseline: 1.0397x; 1.0397x over previous
//
#include <hip/hip_runtime.h>

// Problem constants
#define B_   8
#define T1_  4
#define TP_  3
#define TF_  4
#define C_   256
#define HW_  4096

// Workspace layout (bytes)
#define OFF_FP     0ull          // feature_p bf16: 8*4*256*4096*2 = 67108864
#define OFF_PMAXK  67108864ull   // fp pool max keys (uint) B*TP*C = 24576 B
#define OFF_PSUM   67133440ull   // fp pool sums (float)              24576 B
#define OFF_RMAX   67158016ull   // raw pool max (float) B*C           8192 B
#define OFF_RSUM   67166208ull   // raw pool sum (float)               8192 B
#define OFF_Q      67174400ull   // q: B*TF*C floats                  32768 B
#define OFF_K      67207168ull   // k: B*TP*C floats                  24576 B
#define OFF_AW     67231744ull   // attn_w: B*TF*TP floats              384 B
#define OFF_WFRAG  67232128ull   // W bf16 fragment-order: 65536*2 = 131072 B
#define WS_NEED    67363200ull

typedef __attribute__((ext_vector_type(8))) short bf16x8;
typedef __attribute__((ext_vector_type(4))) float f32x4;

__device__ __forceinline__ unsigned short f2bf(float f) {
    unsigned int u = __float_as_uint(f);
    u += 0x7fffu + ((u >> 16) & 1u);        // RNE
    return (unsigned short)(u >> 16);
}
__device__ __forceinline__ unsigned int cvtpk(float lo, float hi) {
    // D[15:0]=bf16(lo), D[31:16]=bf16(hi), RNE — same bits as f2bf pair
    unsigned int r;
    asm("v_cvt_pk_bf16_f32 %0, %1, %2" : "=v"(r) : "v"(lo), "v"(hi));
    return r;
}
__device__ __forceinline__ unsigned int fkey(float x) {
    unsigned int b = __float_as_uint(x);
    return (b & 0x80000000u) ? ~b : (b | 0x80000000u);
}
__device__ __forceinline__ float funkey(unsigned int k) {
    unsigned int b = (k & 0x80000000u) ? (k ^ 0x80000000u) : ~k;
    return __uint_as_float(b);
}
__device__ __forceinline__ float silu_f(float x) { return x / (1.0f + __expf(-x)); }

__device__ __forceinline__ void dec8(uint4 u, float* f) {
    f[0] = __uint_as_float(u.x << 16); f[1] = __uint_as_float(u.x & 0xffff0000u);
    f[2] = __uint_as_float(u.y << 16); f[3] = __uint_as_float(u.y & 0xffff0000u);
    f[4] = __uint_as_float(u.z << 16); f[5] = __uint_as_float(u.z & 0xffff0000u);
    f[6] = __uint_as_float(u.w << 16); f[7] = __uint_as_float(u.w & 0xffff0000u);
}

// ---------------- k_wpre: W fp32 -> bf16 in MFMA A-fragment order ------------
// Fragment-linear layout: 16B frag index fi = (s*16 + ob)*64 + (q*16 + col),
// element j of that frag = W[ob*16 + col][32*s + 8*q + j].
__global__ __launch_bounds__(256) void k_wpre(const float* __restrict__ Wc,
                                              unsigned short* __restrict__ wfrag) {
    const int idx = blockIdx.x * 256 + threadIdx.x;   // 0..65535 (coalesced writes)
    const int j   = idx & 7;
    const int fi  = idx >> 3;
    const int col = fi & 15;
    const int q   = (fi >> 4) & 3;
    const int sob = fi >> 6;
    const int ob  = sob & 15;
    const int s   = sob >> 4;
    const int o   = ob * 16 + col;
    const int c   = s * 32 + q * 8 + j;
    wfrag[idx] = f2bf(Wc[o * 256 + c]);
}

// ---------------- K0: pool raw feature[:, 3] over HW (max & sum per (b,c)) ----
__global__ __launch_bounds__(256) void k0_rawpool(const float* __restrict__ feature,
                                                  float* __restrict__ rmax,
                                                  float* __restrict__ rsum) {
    const int blk = blockIdx.x;           // 2048 = B * C
    const int b = blk >> 8, c = blk & 255;
    const float* base = feature + ((size_t)(b * 4 + 3) * C_ + c) * HW_;
    const int tid = threadIdx.x;
    float mx = -3.4e38f, sm = 0.0f;
    #pragma unroll
    for (int k = 0; k < 4; ++k) {
        float4 v = *(const float4*)(base + (k * 256 + tid) * 4);
        mx = fmaxf(mx, fmaxf(fmaxf(v.x, v.y), fmaxf(v.z, v.w)));
        sm += (v.x + v.y) + (v.z + v.w);
    }
    #pragma unroll
    for (int m = 1; m < 64; m <<= 1) {
        mx = fmaxf(mx, __shfl_xor(mx, m));
        sm += __shfl_xor(sm, m);
    }
    __shared__ float wmx[4], wsm[4];
    const int wave = tid >> 6;
    if ((tid & 63) == 0) { wmx[wave] = mx; wsm[wave] = sm; }
    __syncthreads();
    if (tid == 0) {
        rmax[b * C_ + c] = fmaxf(fmaxf(wmx[0], wmx[1]), fmaxf(wmx[2], wmx[3]));
        rsum[b * C_ + c] = (wsm[0] + wsm[1]) + (wsm[2] + wsm[3]);
    }
}

// ---------------- K1: conv(1x1) + BN + silu -> feature_p (bf16) + fp pooling ---
// Round-1 structure (LDS B-staging, A frags direct from L2-hot wfrag), trimmed
// to fit the 128-total-reg occupancy band: no A-prefetch register set (A is
// L2-hot; its latency hides under the staging barrier), and
// __launch_bounds__(256,4) forces arch-VGPR <= 64 so VGPR(<=64)+AGPR(64)
// allocates 128 -> 4 waves/SIMD (2x the measured 26% occupancy of r1/r2).
__global__ __launch_bounds__(256, 4) void k1_conv(
    const float* __restrict__ feature, const unsigned short* __restrict__ wfrag,
    const float* __restrict__ gamma, const float* __restrict__ beta,
    const float* __restrict__ mean, const float* __restrict__ var,
    unsigned short* __restrict__ fp_out,
    unsigned int* __restrict__ pmaxk, float* __restrict__ psum) {
    __shared__ __align__(16) unsigned short lds_b[64 * 40];   // 5120 B
    __shared__ float s_scale[256];
    __shared__ float s_shift[256];

    const int tid   = threadIdx.x;
    const int bt    = blockIdx.x >> 6;       // (b,t) 0..31
    const int hwblk = blockIdx.x & 63;
    const int b = bt >> 2, t = bt & 3;
    const int hw0 = hwblk * 64;
    const int lane = tid & 63;
    const int wave = tid >> 6;               // o-quadrant AND B-staging k-group
    const int q = lane >> 4;
    const int col = lane & 15;
    const int hwl = tid & 63;

    {
        float sc = gamma[tid] * rsqrtf(var[tid] + 1e-3f);
        s_scale[tid] = sc;
        s_shift[tid] = beta[tid] - mean[tid] * sc;
    }

    const float* Fb = feature + (size_t)bt * C_ * HW_;
    f32x4 acc[4][4] = {};

    // prologue: step-0 B rows (fp32)
    float fv[8];
    #pragma unroll
    for (int j = 0; j < 8; ++j)
        fv[j] = Fb[(size_t)(wave * 8 + j) * HW_ + hw0 + hwl];

    #pragma unroll
    for (int s = 0; s < 8; ++s) {
        // issue this step's A frags first (no deps; latency hides under staging)
        bf16x8 afr[4];
        #pragma unroll
        for (int mi = 0; mi < 4; ++mi)
            afr[mi] = *(const bf16x8*)(wfrag +
                       ((size_t)((s * 16 + wave * 4 + mi) * 64) + lane) * 8);

        __syncthreads();                       // prev-step frag reads done
        uint4 pk;
        pk.x = cvtpk(fv[0], fv[1]);
        pk.y = cvtpk(fv[2], fv[3]);
        pk.z = cvtpk(fv[4], fv[5]);
        pk.w = cvtpk(fv[6], fv[7]);
        *(uint4*)&lds_b[hwl * 40 + wave * 8] = pk;
        __syncthreads();                       // B tile visible

        bf16x8 bfr[4];
        #pragma unroll
        for (int ni = 0; ni < 4; ++ni)
            bfr[ni] = *(const bf16x8*)&lds_b[(ni * 16 + col) * 40 + q * 8];

        if (s < 7) {                           // prefetch next-step B rows
            #pragma unroll
            for (int j = 0; j < 8; ++j)
                fv[j] = Fb[(size_t)((s + 1) * 32 + wave * 8 + j) * HW_ + hw0 + hwl];
        }

        #pragma unroll
        for (int mi = 0; mi < 4; ++mi)
            #pragma unroll
            for (int ni = 0; ni < 4; ++ni)
                acc[mi][ni] = __builtin_amdgcn_mfma_f32_16x16x32_bf16(
                    afr[mi], bfr[ni], acc[mi][ni], 0, 0, 0);
    }

    // epilogue: BN + silu, store bf16; pooling via quarter-wave shuffle reduce
    unsigned short* fpo = fp_out + (size_t)bt * C_ * HW_;
    #pragma unroll
    for (int mi = 0; mi < 4; ++mi) {
        #pragma unroll
        for (int r = 0; r < 4; ++r) {
            const int o = wave * 64 + mi * 16 + q * 4 + r;   // quarter-uniform
            const float sc = s_scale[o], sh = s_shift[o];
            float mx = -3.4e38f, sm = 0.0f;
            #pragma unroll
            for (int ni = 0; ni < 4; ++ni) {
                float x = acc[mi][ni][r] * sc + sh;
                float sl = silu_f(x);
                fpo[(size_t)o * HW_ + hw0 + ni * 16 + col] = f2bf(sl);
                mx = fmaxf(mx, sl);
                sm += sl;
            }
            if (t < 3) {
                #pragma unroll
                for (int m = 1; m < 16; m <<= 1) {   // reduce over col (intra-quarter)
                    mx = fmaxf(mx, __shfl_xor(mx, m));
                    sm += __shfl_xor(sm, m);
                }
                if (col == 0) {
                    atomicMax(&pmaxk[(b * 3 + t) * C_ + o], fkey(mx));
                    atomicAdd(&psum[(b * 3 + t) * C_ + o], sm);
                }
            }
        }
    }
}

// ---------------- K2a: attn_in (p and f sides) -> k / q (all fp32) -------------
__global__ __launch_bounds__(256) void k2_vec(
    const float* __restrict__ past_tc, const float* __restrict__ fut_tc,
    const float* __restrict__ w_tc, const float* __restrict__ b_tc,
    const float* __restrict__ w_in, const float* __restrict__ b_in,
    const float* __restrict__ w_q, const float* __restrict__ b_q,
    const float* __restrict__ w_k, const float* __restrict__ b_k,
    const unsigned int* __restrict__ pmaxk, const float* __restrict__ psum,
    const float* __restrict__ rmax, const float* __restrict__ rsum,
    float* __restrict__ qout, float* __restrict__ kout) {
    __shared__ float pool[512];
    __shared__ float avec[256];
    const int b = blockIdx.x / 7;
    const int idx = blockIdx.x % 7;      // 0..2 = p-side t, 3..6 = f-side f
    const int o = threadIdx.x;
    const bool pside = (idx < 3);
    if (pside) {
        pool[o]       = funkey(pmaxk[(b * 3 + idx) * C_ + o]);
        pool[256 + o] = psum[(b * 3 + idx) * C_ + o] * (1.0f / 4096.0f);
    } else {
        pool[o]       = rmax[b * C_ + o];
        pool[256 + o] = rsum[b * C_ + o] * (1.0f / 4096.0f);
    }
    __syncthreads();
    float s = b_in[o];
    const float* wr = w_in + (size_t)o * 512;
    #pragma unroll 8
    for (int c = 0; c < 512; ++c) s += wr[c] * pool[c];
    float v = silu_f(s);
    float tcin = pside ? past_tc[b * 3 + idx] : fut_tc[b * 4 + (idx - 3)];
    float tc = tanhf(tcin * w_tc[o] + b_tc[o]);
    avec[o] = v + tc;
    __syncthreads();
    if (pside) {
        float s2 = b_k[o];
        const float* wk = w_k + (size_t)o * 256;
        #pragma unroll 8
        for (int c = 0; c < 256; ++c) s2 += wk[c] * avec[c];
        kout[(b * 3 + idx) * C_ + o] = s2;
    } else {
        float s2 = b_q[o];
        const float* wq = w_q + (size_t)o * 256;
        #pragma unroll 8
        for (int c = 0; c < 256; ++c) s2 += wq[c] * avec[c];
        qout[(b * 4 + (idx - 3)) * C_ + o] = s2;
    }
}

// ---------------- K2b: attn_w[b][f][p] = q.k / sqrt(TF) -----------------------
__global__ __launch_bounds__(64) void k2_attnw(const float* __restrict__ qv,
                                               const float* __restrict__ kv,
                                               float* __restrict__ aw) {
    const int i = blockIdx.x;            // 96 = B*TF*TP
    const int b = i / 12, rr = i % 12, f = rr / 3, p = rr % 3;
    const int lane = threadIdx.x;
    const float* qp = qv + (b * 4 + f) * C_;
    const float* kp = kv + (b * 3 + p) * C_;
    float s = 0.0f;
    #pragma unroll
    for (int j = 0; j < 4; ++j) s += qp[lane + 64 * j] * kp[lane + 64 * j];
    #pragma unroll
    for (int m = 1; m < 64; m <<= 1) s += __shfl_xor(s, m);
    if (lane == 0) aw[b * 12 + rr] = s * 0.5f;   // / sqrt(TF=4)
}

// ---------------- K3: out = last + (p_attn/TP) * sum_p aw*(fp3 - fp_p) --------
__global__ __launch_bounds__(256) void k3_out(
    const float* __restrict__ feature, const unsigned short* __restrict__ fp,
    const float* __restrict__ aw, const float* __restrict__ p_attn,
    float* __restrict__ out) {
    const int idx = blockIdx.x;              // 4096 = B * C * 2
    const int b = idx >> 9;
    const int c = (idx >> 1) & 255;
    const int half = idx & 1;
    const int hw = half * 2048 + threadIdx.x * 8;

    float a[12];
    #pragma unroll
    for (int i = 0; i < 12; ++i) a[i] = aw[b * 12 + i];
    const float pa = p_attn[c] * (1.0f / 3.0f);

    const size_t ts = (size_t)C_ * HW_;
    const size_t base = ((size_t)(b * 4) * C_ + c) * HW_ + hw;

    uint4 u0 = *(const uint4*)(fp + base);
    uint4 u1 = *(const uint4*)(fp + base + ts);
    uint4 u2 = *(const uint4*)(fp + base + 2 * ts);
    uint4 u3 = *(const uint4*)(fp + base + 3 * ts);
    float4 l0 = *(const float4*)(feature + base + 3 * ts);
    float4 l1 = *(const float4*)(feature + base + 3 * ts + 4);

    float f0[8], f1[8], f2[8], f3[8];
    dec8(u0, f0); dec8(u1, f1); dec8(u2, f2); dec8(u3, f3);
    float lastv[8] = {l0.x, l0.y, l0.z, l0.w, l1.x, l1.y, l1.z, l1.w};

    float ov[4][8];
    #pragma unroll
    for (int e = 0; e < 8; ++e) {
        float d0 = f3[e] - f0[e];
        float d1 = f3[e] - f1[e];
        float d2 = f3[e] - f2[e];
        #pragma unroll
        for (int f = 0; f < 4; ++f) {
            float at = a[f * 3 + 0] * d0 + a[f * 3 + 1] * d1 + a[f * 3 + 2] * d2;
            ov[f][e] = lastv[e] + at * pa;
        }
    }
    #pragma unroll
    for (int f = 0; f < 4; ++f) {
        size_t ob = ((size_t)(b * 4 + f) * C_ + c) * HW_ + hw;
        *(float4*)(out + ob)     = make_float4(ov[f][0], ov[f][1], ov[f][2], ov[f][3]);
        *(float4*)(out + ob + 4) = make_float4(ov[f][4], ov[f][5], ov[f][6], ov[f][7]);
    }
}

extern "C" void kernel_launch(void* const* d_in, const int* in_sizes, int n_in,
                              void* d_out, int out_size, void* d_ws, size_t ws_size,
                              hipStream_t stream) {
    const float* feature = (const float*)d_in[0];
    const float* past_tc = (const float*)d_in[1];
    const float* fut_tc  = (const float*)d_in[2];
    const float* w_tc    = (const float*)d_in[3];
    const float* b_tc    = (const float*)d_in[4];
    const float* w_in    = (const float*)d_in[5];
    const float* b_in    = (const float*)d_in[6];
    const float* conv_w  = (const float*)d_in[7];
    const float* gamma   = (const float*)d_in[8];
    const float* beta    = (const float*)d_in[9];
    const float* mean    = (const float*)d_in[10];
    const float* var     = (const float*)d_in[11];
    const float* w_q     = (const float*)d_in[12];
    const float* b_q     = (const float*)d_in[13];
    const float* w_k     = (const float*)d_in[14];
    const float* b_k     = (const float*)d_in[15];
    const float* p_attn  = (const float*)d_in[16];

    char* ws = (char*)d_ws;
    unsigned short* fp  = (unsigned short*)(ws + OFF_FP);
    unsigned int* pmaxk = (unsigned int*)(ws + OFF_PMAXK);
    float* psum = (float*)(ws + OFF_PSUM);
    float* rmax = (float*)(ws + OFF_RMAX);
    float* rsum = (float*)(ws + OFF_RSUM);
    float* qout = (float*)(ws + OFF_Q);
    float* kout = (float*)(ws + OFF_K);
    float* aw   = (float*)(ws + OFF_AW);
    // W fragment buffer: workspace if it fits, else scratch in the (not yet
    // written) tail of d_out — k1 finishes reading it before k3 writes out.
    unsigned short* wfrag = (ws_size >= WS_NEED)
        ? (unsigned short*)(ws + OFF_WFRAG)
        : (unsigned short*)((char*)d_out + (size_t)out_size - 131072);

    // zero the fp-pool accumulators (maxkey 0 == below all finite floats; sum 0.0f)
    hipMemsetAsync(ws + OFF_PMAXK, 0, 49152, stream);

    k_wpre<<<256, 256, 0, stream>>>(conv_w, wfrag);
    k0_rawpool<<<B_ * C_, 256, 0, stream>>>(feature, rmax, rsum);
    k1_conv<<<B_ * T1_ * 64, 256, 0, stream>>>(feature, wfrag, gamma, beta, mean, var,
                                               fp, pmaxk, psum);
    k2_vec<<<B_ * 7, 256, 0, stream>>>(past_tc, fut_tc, w_tc, b_tc, w_in, b_in,
                                       w_q, b_q, w_k, b_k, pmaxk, psum, rmax, rsum,
                                       qout, kout);
    k2_attnw<<<B_ * TF_ * TP_, 64, 0, stream>>>(qout, kout, aw);
    k3_out<<<B_ * C_ * 2, 256, 0, stream>>>(feature, fp, aw, p_attn, (float*)d_out);
}

// Round 4
// 349.491 us; speedup vs baseline: 1.0550x; 1.0147x over previous
//
#include <hip/hip_runtime.h>

// Problem constants
#define B_   8
#define T1_  4
#define TP_  3
#define TF_  4
#define C_   256
#define HW_  4096

// Workspace layout (bytes)
#define OFF_FP     0ull          // feature_p bf16: 8*4*256*4096*2 = 67108864
#define OFF_PMAXK  67108864ull   // fp pool max keys (uint) B*TP*C = 24576 B
#define OFF_PSUM   67133440ull   // fp pool sums (float)              24576 B
#define OFF_RMAX   67158016ull   // raw pool max (float) B*C           8192 B
#define OFF_RSUM   67166208ull   // raw pool sum (float)               8192 B
#define OFF_Q      67174400ull   // q: B*TF*C floats                  32768 B
#define OFF_K      67207168ull   // k: B*TP*C floats                  24576 B
#define OFF_AW     67231744ull   // attn_w: B*TF*TP floats              384 B
#define OFF_WFRAG  67232128ull   // W bf16 fragment-order: 65536*2 = 131072 B
#define WS_NEED    67363200ull

typedef __attribute__((ext_vector_type(8))) short bf16x8;
typedef __attribute__((ext_vector_type(4))) float f32x4;

__device__ __forceinline__ unsigned short f2bf(float f) {
    unsigned int u = __float_as_uint(f);
    u += 0x7fffu + ((u >> 16) & 1u);        // RNE
    return (unsigned short)(u >> 16);
}
__device__ __forceinline__ unsigned int cvtpk(float lo, float hi) {
    // D[15:0]=bf16(lo), D[31:16]=bf16(hi), RNE — same bits as f2bf pair
    unsigned int r;
    asm("v_cvt_pk_bf16_f32 %0, %1, %2" : "=v"(r) : "v"(lo), "v"(hi));
    return r;
}
__device__ __forceinline__ unsigned int fkey(float x) {
    unsigned int b = __float_as_uint(x);
    return (b & 0x80000000u) ? ~b : (b | 0x80000000u);
}
__device__ __forceinline__ float funkey(unsigned int k) {
    unsigned int b = (k & 0x80000000u) ? (k ^ 0x80000000u) : ~k;
    return __uint_as_float(b);
}
__device__ __forceinline__ float silu_f(float x) { return x / (1.0f + __expf(-x)); }

__device__ __forceinline__ void dec8(uint4 u, float* f) {
    f[0] = __uint_as_float(u.x << 16); f[1] = __uint_as_float(u.x & 0xffff0000u);
    f[2] = __uint_as_float(u.y << 16); f[3] = __uint_as_float(u.y & 0xffff0000u);
    f[4] = __uint_as_float(u.z << 16); f[5] = __uint_as_float(u.z & 0xffff0000u);
    f[6] = __uint_as_float(u.w << 16); f[7] = __uint_as_float(u.w & 0xffff0000u);
}

// ---------------- k_wpre: W fp32 -> bf16 in MFMA A-fragment order ------------
// Fragment-linear layout: 16B frag index fi = (s*16 + ob)*64 + (q*16 + col),
// element j of that frag = W[ob*16 + col][32*s + 8*q + j].
__global__ __launch_bounds__(256) void k_wpre(const float* __restrict__ Wc,
                                              unsigned short* __restrict__ wfrag) {
    const int idx = blockIdx.x * 256 + threadIdx.x;   // 0..65535 (coalesced writes)
    const int j   = idx & 7;
    const int fi  = idx >> 3;
    const int col = fi & 15;
    const int q   = (fi >> 4) & 3;
    const int sob = fi >> 6;
    const int ob  = sob & 15;
    const int s   = sob >> 4;
    const int o   = ob * 16 + col;
    const int c   = s * 32 + q * 8 + j;
    wfrag[idx] = f2bf(Wc[o * 256 + c]);
}

// ---------------- K0: pool raw feature[:, 3] over HW (max & sum per (b,c)) ----
__global__ __launch_bounds__(256) void k0_rawpool(const float* __restrict__ feature,
                                                  float* __restrict__ rmax,
                                                  float* __restrict__ rsum) {
    const int blk = blockIdx.x;           // 2048 = B * C
    const int b = blk >> 8, c = blk & 255;
    const float* base = feature + ((size_t)(b * 4 + 3) * C_ + c) * HW_;
    const int tid = threadIdx.x;
    float mx = -3.4e38f, sm = 0.0f;
    #pragma unroll
    for (int k = 0; k < 4; ++k) {
        float4 v = *(const float4*)(base + (k * 256 + tid) * 4);
        mx = fmaxf(mx, fmaxf(fmaxf(v.x, v.y), fmaxf(v.z, v.w)));
        sm += (v.x + v.y) + (v.z + v.w);
    }
    #pragma unroll
    for (int m = 1; m < 64; m <<= 1) {
        mx = fmaxf(mx, __shfl_xor(mx, m));
        sm += __shfl_xor(sm, m);
    }
    __shared__ float wmx[4], wsm[4];
    const int wave = tid >> 6;
    if ((tid & 63) == 0) { wmx[wave] = mx; wsm[wave] = sm; }
    __syncthreads();
    if (tid == 0) {
        rmax[b * C_ + c] = fmaxf(fmaxf(wmx[0], wmx[1]), fmaxf(wmx[2], wmx[3]));
        rsum[b * C_ + c] = (wsm[0] + wsm[1]) + (wsm[2] + wsm[3]);
    }
}

// ---------------- K1: conv(1x1) + BN + silu -> feature_p (bf16) + fp pooling ---
// Round-3 structure (LDS B-staging, A frags direct from L2-hot wfrag) with the
// B-prefetch deepened from 1 step to 3 steps: fv ring holds steps s..s+2 in
// flight, loads for s+3 issue at step s (~600cy of cover vs ~900cy HBM
// latency). launch_bounds(256,3): ~3 waves/SIMD with the +24 prefetch VGPRs.
__global__ __launch_bounds__(256, 3) void k1_conv(
    const float* __restrict__ feature, const unsigned short* __restrict__ wfrag,
    const float* __restrict__ gamma, const float* __restrict__ beta,
    const float* __restrict__ mean, const float* __restrict__ var,
    unsigned short* __restrict__ fp_out,
    unsigned int* __restrict__ pmaxk, float* __restrict__ psum) {
    __shared__ __align__(16) unsigned short lds_b[64 * 40];   // 5120 B
    __shared__ float s_scale[256];
    __shared__ float s_shift[256];

    const int tid   = threadIdx.x;
    const int bt    = blockIdx.x >> 6;       // (b,t) 0..31
    const int hwblk = blockIdx.x & 63;
    const int b = bt >> 2, t = bt & 3;
    const int hw0 = hwblk * 64;
    const int lane = tid & 63;
    const int wave = tid >> 6;               // o-quadrant AND B-staging k-group
    const int q = lane >> 4;
    const int col = lane & 15;
    const int hwl = tid & 63;

    {
        float sc = gamma[tid] * rsqrtf(var[tid] + 1e-3f);
        s_scale[tid] = sc;
        s_shift[tid] = beta[tid] - mean[tid] * sc;
    }

    const float* Fb = feature + (size_t)bt * C_ * HW_;
    f32x4 acc[4][4] = {};

    // prologue: preload B rows for steps 0,1,2 (depth-3 ring)
    float fv[3][8];
    #pragma unroll
    for (int p = 0; p < 3; ++p)
        #pragma unroll
        for (int j = 0; j < 8; ++j)
            fv[p][j] = Fb[(size_t)(p * 32 + wave * 8 + j) * HW_ + hw0 + hwl];

    #pragma unroll
    for (int s = 0; s < 8; ++s) {
        // this step's A frags (L2-hot; latency hides under barrier+staging)
        bf16x8 afr[4];
        #pragma unroll
        for (int mi = 0; mi < 4; ++mi)
            afr[mi] = *(const bf16x8*)(wfrag +
                       ((size_t)((s * 16 + wave * 4 + mi) * 64) + lane) * 8);

        __syncthreads();                       // prev-step frag reads done
        const int slot = s % 3;                // static under full unroll
        uint4 pk;
        pk.x = cvtpk(fv[slot][0], fv[slot][1]);
        pk.y = cvtpk(fv[slot][2], fv[slot][3]);
        pk.z = cvtpk(fv[slot][4], fv[slot][5]);
        pk.w = cvtpk(fv[slot][6], fv[slot][7]);
        *(uint4*)&lds_b[hwl * 40 + wave * 8] = pk;

        // refill the consumed slot with step s+3's B rows (issues early,
        // returns ~3 steps later)
        if (s + 3 < 8) {
            #pragma unroll
            for (int j = 0; j < 8; ++j)
                fv[slot][j] = Fb[(size_t)((s + 3) * 32 + wave * 8 + j) * HW_
                                 + hw0 + hwl];
        }

        __syncthreads();                       // B tile visible

        bf16x8 bfr[4];
        #pragma unroll
        for (int ni = 0; ni < 4; ++ni)
            bfr[ni] = *(const bf16x8*)&lds_b[(ni * 16 + col) * 40 + q * 8];

        #pragma unroll
        for (int mi = 0; mi < 4; ++mi)
            #pragma unroll
            for (int ni = 0; ni < 4; ++ni)
                acc[mi][ni] = __builtin_amdgcn_mfma_f32_16x16x32_bf16(
                    afr[mi], bfr[ni], acc[mi][ni], 0, 0, 0);
    }

    // epilogue: BN + silu, store bf16; pooling via quarter-wave shuffle reduce
    unsigned short* fpo = fp_out + (size_t)bt * C_ * HW_;
    #pragma unroll
    for (int mi = 0; mi < 4; ++mi) {
        #pragma unroll
        for (int r = 0; r < 4; ++r) {
            const int o = wave * 64 + mi * 16 + q * 4 + r;   // quarter-uniform
            const float sc = s_scale[o], sh = s_shift[o];
            float mx = -3.4e38f, sm = 0.0f;
            #pragma unroll
            for (int ni = 0; ni < 4; ++ni) {
                float x = acc[mi][ni][r] * sc + sh;
                float sl = silu_f(x);
                fpo[(size_t)o * HW_ + hw0 + ni * 16 + col] = f2bf(sl);
                mx = fmaxf(mx, sl);
                sm += sl;
            }
            if (t < 3) {
                #pragma unroll
                for (int m = 1; m < 16; m <<= 1) {   // reduce over col (intra-quarter)
                    mx = fmaxf(mx, __shfl_xor(mx, m));
                    sm += __shfl_xor(sm, m);
                }
                if (col == 0) {
                    atomicMax(&pmaxk[(b * 3 + t) * C_ + o], fkey(mx));
                    atomicAdd(&psum[(b * 3 + t) * C_ + o], sm);
                }
            }
        }
    }
}

// ---------------- K2a: attn_in (p and f sides) -> k / q (all fp32) -------------
__global__ __launch_bounds__(256) void k2_vec(
    const float* __restrict__ past_tc, const float* __restrict__ fut_tc,
    const float* __restrict__ w_tc, const float* __restrict__ b_tc,
    const float* __restrict__ w_in, const float* __restrict__ b_in,
    const float* __restrict__ w_q, const float* __restrict__ b_q,
    const float* __restrict__ w_k, const float* __restrict__ b_k,
    const unsigned int* __restrict__ pmaxk, const float* __restrict__ psum,
    const float* __restrict__ rmax, const float* __restrict__ rsum,
    float* __restrict__ qout, float* __restrict__ kout) {
    __shared__ float pool[512];
    __shared__ float avec[256];
    const int b = blockIdx.x / 7;
    const int idx = blockIdx.x % 7;      // 0..2 = p-side t, 3..6 = f-side f
    const int o = threadIdx.x;
    const bool pside = (idx < 3);
    if (pside) {
        pool[o]       = funkey(pmaxk[(b * 3 + idx) * C_ + o]);
        pool[256 + o] = psum[(b * 3 + idx) * C_ + o] * (1.0f / 4096.0f);
    } else {
        pool[o]       = rmax[b * C_ + o];
        pool[256 + o] = rsum[b * C_ + o] * (1.0f / 4096.0f);
    }
    __syncthreads();
    float s = b_in[o];
    const float* wr = w_in + (size_t)o * 512;
    #pragma unroll 8
    for (int c = 0; c < 512; ++c) s += wr[c] * pool[c];
    float v = silu_f(s);
    float tcin = pside ? past_tc[b * 3 + idx] : fut_tc[b * 4 + (idx - 3)];
    float tc = tanhf(tcin * w_tc[o] + b_tc[o]);
    avec[o] = v + tc;
    __syncthreads();
    if (pside) {
        float s2 = b_k[o];
        const float* wk = w_k + (size_t)o * 256;
        #pragma unroll 8
        for (int c = 0; c < 256; ++c) s2 += wk[c] * avec[c];
        kout[(b * 3 + idx) * C_ + o] = s2;
    } else {
        float s2 = b_q[o];
        const float* wq = w_q + (size_t)o * 256;
        #pragma unroll 8
        for (int c = 0; c < 256; ++c) s2 += wq[c] * avec[c];
        qout[(b * 4 + (idx - 3)) * C_ + o] = s2;
    }
}

// ---------------- K2b: attn_w[b][f][p] = q.k / sqrt(TF) -----------------------
__global__ __launch_bounds__(64) void k2_attnw(const float* __restrict__ qv,
                                               const float* __restrict__ kv,
                                               float* __restrict__ aw) {
    const int i = blockIdx.x;            // 96 = B*TF*TP
    const int b = i / 12, rr = i % 12, f = rr / 3, p = rr % 3;
    const int lane = threadIdx.x;
    const float* qp = qv + (b * 4 + f) * C_;
    const float* kp = kv + (b * 3 + p) * C_;
    float s = 0.0f;
    #pragma unroll
    for (int j = 0; j < 4; ++j) s += qp[lane + 64 * j] * kp[lane + 64 * j];
    #pragma unroll
    for (int m = 1; m < 64; m <<= 1) s += __shfl_xor(s, m);
    if (lane == 0) aw[b * 12 + rr] = s * 0.5f;   // / sqrt(TF=4)
}

// ---------------- K3: out = last + (p_attn/TP) * sum_p aw*(fp3 - fp_p) --------
__global__ __launch_bounds__(256) void k3_out(
    const float* __restrict__ feature, const unsigned short* __restrict__ fp,
    const float* __restrict__ aw, const float* __restrict__ p_attn,
    float* __restrict__ out) {
    const int idx = blockIdx.x;              // 4096 = B * C * 2
    const int b = idx >> 9;
    const int c = (idx >> 1) & 255;
    const int half = idx & 1;
    const int hw = half * 2048 + threadIdx.x * 8;

    float a[12];
    #pragma unroll
    for (int i = 0; i < 12; ++i) a[i] = aw[b * 12 + i];
    const float pa = p_attn[c] * (1.0f / 3.0f);

    const size_t ts = (size_t)C_ * HW_;
    const size_t base = ((size_t)(b * 4) * C_ + c) * HW_ + hw;

    uint4 u0 = *(const uint4*)(fp + base);
    uint4 u1 = *(const uint4*)(fp + base + ts);
    uint4 u2 = *(const uint4*)(fp + base + 2 * ts);
    uint4 u3 = *(const uint4*)(fp + base + 3 * ts);
    float4 l0 = *(const float4*)(feature + base + 3 * ts);
    float4 l1 = *(const float4*)(feature + base + 3 * ts + 4);

    float f0[8], f1[8], f2[8], f3[8];
    dec8(u0, f0); dec8(u1, f1); dec8(u2, f2); dec8(u3, f3);
    float lastv[8] = {l0.x, l0.y, l0.z, l0.w, l1.x, l1.y, l1.z, l1.w};

    float ov[4][8];
    #pragma unroll
    for (int e = 0; e < 8; ++e) {
        float d0 = f3[e] - f0[e];
        float d1 = f3[e] - f1[e];
        float d2 = f3[e] - f2[e];
        #pragma unroll
        for (int f = 0; f < 4; ++f) {
            float at = a[f * 3 + 0] * d0 + a[f * 3 + 1] * d1 + a[f * 3 + 2] * d2;
            ov[f][e] = lastv[e] + at * pa;
        }
    }
    #pragma unroll
    for (int f = 0; f < 4; ++f) {
        size_t ob = ((size_t)(b * 4 + f) * C_ + c) * HW_ + hw;
        *(float4*)(out + ob)     = make_float4(ov[f][0], ov[f][1], ov[f][2], ov[f][3]);
        *(float4*)(out + ob + 4) = make_float4(ov[f][4], ov[f][5], ov[f][6], ov[f][7]);
    }
}

extern "C" void kernel_launch(void* const* d_in, const int* in_sizes, int n_in,
                              void* d_out, int out_size, void* d_ws, size_t ws_size,
                              hipStream_t stream) {
    const float* feature = (const float*)d_in[0];
    const float* past_tc = (const float*)d_in[1];
    const float* fut_tc  = (const float*)d_in[2];
    const float* w_tc    = (const float*)d_in[3];
    const float* b_tc    = (const float*)d_in[4];
    const float* w_in    = (const float*)d_in[5];
    const float* b_in    = (const float*)d_in[6];
    const float* conv_w  = (const float*)d_in[7];
    const float* gamma   = (const float*)d_in[8];
    const float* beta    = (const float*)d_in[9];
    const float* mean    = (const float*)d_in[10];
    const float* var     = (const float*)d_in[11];
    const float* w_q     = (const float*)d_in[12];
    const float* b_q     = (const float*)d_in[13];
    const float* w_k     = (const float*)d_in[14];
    const float* b_k     = (const float*)d_in[15];
    const float* p_attn  = (const float*)d_in[16];

    char* ws = (char*)d_ws;
    unsigned short* fp  = (unsigned short*)(ws + OFF_FP);
    unsigned int* pmaxk = (unsigned int*)(ws + OFF_PMAXK);
    float* psum = (float*)(ws + OFF_PSUM);
    float* rmax = (float*)(ws + OFF_RMAX);
    float* rsum = (float*)(ws + OFF_RSUM);
    float* qout = (float*)(ws + OFF_Q);
    float* kout = (float*)(ws + OFF_K);
    float* aw   = (float*)(ws + OFF_AW);
    // W fragment buffer: workspace if it fits, else scratch in the (not yet
    // written) tail of d_out — k1 finishes reading it before k3 writes out.
    unsigned short* wfrag = (ws_size >= WS_NEED)
        ? (unsigned short*)(ws + OFF_WFRAG)
        : (unsigned short*)((char*)d_out + (size_t)out_size - 131072);

    // zero the fp-pool accumulators (maxkey 0 == below all finite floats; sum 0.0f)
    hipMemsetAsync(ws + OFF_PMAXK, 0, 49152, stream);

    k_wpre<<<256, 256, 0, stream>>>(conv_w, wfrag);
    k0_rawpool<<<B_ * C_, 256, 0, stream>>>(feature, rmax, rsum);
    k1_conv<<<B_ * T1_ * 64, 256, 0, stream>>>(feature, wfrag, gamma, beta, mean, var,
                                               fp, pmaxk, psum);
    k2_vec<<<B_ * 7, 256, 0, stream>>>(past_tc, fut_tc, w_tc, b_tc, w_in, b_in,
                                       w_q, b_q, w_k, b_k, pmaxk, psum, rmax, rsum,
                                       qout, kout);
    k2_attnw<<<B_ * TF_ * TP_, 64, 0, stream>>>(qout, kout, aw);
    k3_out<<<B_ * C_ * 2, 256, 0, stream>>>(feature, fp, aw, p_attn, (float*)d_out);
}

// Round 6
// 347.042 us; speedup vs baseline: 1.0624x; 1.0071x over previous
//
#include <hip/hip_runtime.h>

// Problem constants
#define B_   8
#define T1_  4
#define TP_  3
#define TF_  4
#define C_   256
#define HW_  4096

// Workspace layout (bytes)
#define OFF_FP     0ull          // feature_p bf16: 8*4*256*4096*2 = 67108864
#define OFF_PMAXK  67108864ull   // fp pool max keys (uint) B*TP*C = 24576 B
#define OFF_PSUM   67133440ull   // fp pool sums (float)              24576 B
#define OFF_RMAX   67158016ull   // raw pool max (float) B*C           8192 B
#define OFF_RSUM   67166208ull   // raw pool sum (float)               8192 B
#define OFF_Q      67174400ull   // q: B*TF*C floats                  32768 B
#define OFF_K      67207168ull   // k: B*TP*C floats                  24576 B
#define OFF_AW     67231744ull   // attn_w: B*TF*TP floats              384 B
#define OFF_WFRAG  67232128ull   // W bf16 fragment-order: 65536*2 = 131072 B
#define WS_NEED    67363200ull

typedef __attribute__((ext_vector_type(8))) short bf16x8;
typedef __attribute__((ext_vector_type(4))) float f32x4;

__device__ __forceinline__ unsigned short f2bf(float f) {
    unsigned int u = __float_as_uint(f);
    u += 0x7fffu + ((u >> 16) & 1u);        // RNE
    return (unsigned short)(u >> 16);
}
__device__ __forceinline__ unsigned int cvtpk(float lo, float hi) {
    // D[15:0]=bf16(lo), D[31:16]=bf16(hi), RNE — same bits as f2bf pair
    unsigned int r;
    asm("v_cvt_pk_bf16_f32 %0, %1, %2" : "=v"(r) : "v"(lo), "v"(hi));
    return r;
}
__device__ __forceinline__ unsigned int fkey(float x) {
    unsigned int b = __float_as_uint(x);
    return (b & 0x80000000u) ? ~b : (b | 0x80000000u);
}
__device__ __forceinline__ float funkey(unsigned int k) {
    unsigned int b = (k & 0x80000000u) ? (k ^ 0x80000000u) : ~k;
    return __uint_as_float(b);
}
__device__ __forceinline__ float silu_f(float x) { return x / (1.0f + __expf(-x)); }

__device__ __forceinline__ void dec8(uint4 u, float* f) {
    f[0] = __uint_as_float(u.x << 16); f[1] = __uint_as_float(u.x & 0xffff0000u);
    f[2] = __uint_as_float(u.y << 16); f[3] = __uint_as_float(u.y & 0xffff0000u);
    f[4] = __uint_as_float(u.z << 16); f[5] = __uint_as_float(u.z & 0xffff0000u);
    f[6] = __uint_as_float(u.w << 16); f[7] = __uint_as_float(u.w & 0xffff0000u);
}

// ---------------- k_wpre: W fp32 -> bf16 in MFMA fragment order ------------
// Fragment-linear layout: 16B frag index fi = (s*16 + ob)*64 + (q*16 + col),
// element j of that frag = W[ob*16 + col][32*s + 8*q + j].
// Used as the MFMA *B* operand: lane(q,col) supplies B[k=q*8+j][n=col]
// = W^T[k][o] — same bits as the A-operand layout W[o=col][k].
__global__ __launch_bounds__(256) void k_wpre(const float* __restrict__ Wc,
                                              unsigned short* __restrict__ wfrag) {
    const int idx = blockIdx.x * 256 + threadIdx.x;   // 0..65535 (coalesced writes)
    const int j   = idx & 7;
    const int fi  = idx >> 3;
    const int col = fi & 15;
    const int q   = (fi >> 4) & 3;
    const int sob = fi >> 6;
    const int ob  = sob & 15;
    const int s   = sob >> 4;
    const int o   = ob * 16 + col;
    const int c   = s * 32 + q * 8 + j;
    wfrag[idx] = f2bf(Wc[o * 256 + c]);
}

// ---------------- K0: pool raw feature[:, 3] over HW (max & sum per (b,c)) ----
__global__ __launch_bounds__(256) void k0_rawpool(const float* __restrict__ feature,
                                                  float* __restrict__ rmax,
                                                  float* __restrict__ rsum) {
    const int blk = blockIdx.x;           // 2048 = B * C
    const int b = blk >> 8, c = blk & 255;
    const float* base = feature + ((size_t)(b * 4 + 3) * C_ + c) * HW_;
    const int tid = threadIdx.x;
    float mx = -3.4e38f, sm = 0.0f;
    #pragma unroll
    for (int k = 0; k < 4; ++k) {
        float4 v = *(const float4*)(base + (k * 256 + tid) * 4);
        mx = fmaxf(mx, fmaxf(fmaxf(v.x, v.y), fmaxf(v.z, v.w)));
        sm += (v.x + v.y) + (v.z + v.w);
    }
    #pragma unroll
    for (int m = 1; m < 64; m <<= 1) {
        mx = fmaxf(mx, __shfl_xor(mx, m));
        sm += __shfl_xor(sm, m);
    }
    __shared__ float wmx[4], wsm[4];
    const int wave = tid >> 6;
    if ((tid & 63) == 0) { wmx[wave] = mx; wsm[wave] = sm; }
    __syncthreads();
    if (tid == 0) {
        rmax[b * C_ + c] = fmaxf(fmaxf(wmx[0], wmx[1]), fmaxf(wmx[2], wmx[3]));
        rsum[b * C_ + c] = (wsm[0] + wsm[1]) + (wsm[2] + wsm[3]);
    }
}

// ---------------- K1: conv(1x1) + BN + silu -> feature_p (bf16) + fp pooling ---
// K-loop identical to round 4 (coop LDS B-staging, depth-3 fv ring, A frags
// from L2-hot wfrag). MFMA operands SWAPPED vs r4: D = mfma(lds_tile, wfrag)
// so D[m=hw][n=o] — lane(q,col) holds 4 CONSECUTIVE hw of o-row `col`.
// Epilogue: 16x dwordx2 stores (was 64x b16), fp32-exact pooling with local
// max/sum over 16 hw + 2 shfl_xor levels (was 4 levels x 16 outputs).
__global__ __launch_bounds__(256, 3) void k1_conv(
    const float* __restrict__ feature, const unsigned short* __restrict__ wfrag,
    const float* __restrict__ gamma, const float* __restrict__ beta,
    const float* __restrict__ mean, const float* __restrict__ var,
    unsigned short* __restrict__ fp_out,
    unsigned int* __restrict__ pmaxk, float* __restrict__ psum) {
    __shared__ __align__(16) unsigned short lds_b[64 * 40];   // 5120 B
    __shared__ float s_scale[256];
    __shared__ float s_shift[256];

    const int tid   = threadIdx.x;
    const int bt    = blockIdx.x >> 6;       // (b,t) 0..31
    const int hwblk = blockIdx.x & 63;
    const int b = bt >> 2, t = bt & 3;
    const int hw0 = hwblk * 64;
    const int lane = tid & 63;
    const int wave = tid >> 6;               // o-quadrant AND B-staging k-group
    const int q = lane >> 4;
    const int col = lane & 15;
    const int hwl = tid & 63;

    {
        float sc = gamma[tid] * rsqrtf(var[tid] + 1e-3f);
        s_scale[tid] = sc;
        s_shift[tid] = beta[tid] - mean[tid] * sc;
    }

    const float* Fb = feature + (size_t)bt * C_ * HW_;
    f32x4 acc[4][4] = {};    // acc[hwtile][otile]

    // prologue: preload B rows for steps 0,1,2 (depth-3 ring)
    float fv[3][8];
    #pragma unroll
    for (int p = 0; p < 3; ++p)
        #pragma unroll
        for (int j = 0; j < 8; ++j)
            fv[p][j] = Fb[(size_t)(p * 32 + wave * 8 + j) * HW_ + hw0 + hwl];

    #pragma unroll
    for (int s = 0; s < 8; ++s) {
        // this step's W frags (L2-hot; latency hides under barrier+staging)
        bf16x8 afr[4];
        #pragma unroll
        for (int mi = 0; mi < 4; ++mi)
            afr[mi] = *(const bf16x8*)(wfrag +
                       ((size_t)((s * 16 + wave * 4 + mi) * 64) + lane) * 8);

        __syncthreads();                       // prev-step frag reads done
        const int slot = s % 3;                // static under full unroll
        uint4 pk;
        pk.x = cvtpk(fv[slot][0], fv[slot][1]);
        pk.y = cvtpk(fv[slot][2], fv[slot][3]);
        pk.z = cvtpk(fv[slot][4], fv[slot][5]);
        pk.w = cvtpk(fv[slot][6], fv[slot][7]);
        *(uint4*)&lds_b[hwl * 40 + wave * 8] = pk;

        // refill the consumed slot with step s+3's B rows (issues early,
        // returns ~3 steps later)
        if (s + 3 < 8) {
            #pragma unroll
            for (int j = 0; j < 8; ++j)
                fv[slot][j] = Fb[(size_t)((s + 3) * 32 + wave * 8 + j) * HW_
                                 + hw0 + hwl];
        }

        __syncthreads();                       // B tile visible

        bf16x8 bfr[4];
        #pragma unroll
        for (int ni = 0; ni < 4; ++ni)
            bfr[ni] = *(const bf16x8*)&lds_b[(ni * 16 + col) * 40 + q * 8];

        // SWAPPED operands: D[m=hw][n=o]
        #pragma unroll
        for (int ni = 0; ni < 4; ++ni)
            #pragma unroll
            for (int mi = 0; mi < 4; ++mi)
                acc[ni][mi] = __builtin_amdgcn_mfma_f32_16x16x32_bf16(
                    bfr[ni], afr[mi], acc[ni][mi], 0, 0, 0);
    }

    // epilogue: lane(q,col) holds D[hw=hi*16+q*4+r][o=wave*64+oi*16+col]
    unsigned short* fpo = fp_out + (size_t)bt * C_ * HW_;
    #pragma unroll
    for (int oi = 0; oi < 4; ++oi) {
        const int o = wave * 64 + oi * 16 + col;
        const float sc = s_scale[o], sh = s_shift[o];
        float mx = -3.4e38f, sm = 0.0f;
        #pragma unroll
        for (int hi = 0; hi < 4; ++hi) {
            float sl[4];
            #pragma unroll
            for (int r = 0; r < 4; ++r) {
                float x = acc[hi][oi][r] * sc + sh;
                sl[r] = silu_f(x);
                mx = fmaxf(mx, sl[r]);
                sm += sl[r];
            }
            uint2 pk2;
            pk2.x = cvtpk(sl[0], sl[1]);
            pk2.y = cvtpk(sl[2], sl[3]);
            *(uint2*)&fpo[(size_t)o * HW_ + hw0 + hi * 16 + q * 4] = pk2;
        }
        if (t < 3) {
            // reduce over q (lane bits 4,5); col preserved -> per-o totals
            mx = fmaxf(mx, __shfl_xor(mx, 16)); sm += __shfl_xor(sm, 16);
            mx = fmaxf(mx, __shfl_xor(mx, 32)); sm += __shfl_xor(sm, 32);
            if (q == 0) {
                atomicMax(&pmaxk[(b * 3 + t) * C_ + o], fkey(mx));
                atomicAdd(&psum[(b * 3 + t) * C_ + o], sm);
            }
        }
    }
}

// ---------------- K2a: attn_in (p and f sides) -> k / q (all fp32) -------------
__global__ __launch_bounds__(256) void k2_vec(
    const float* __restrict__ past_tc, const float* __restrict__ fut_tc,
    const float* __restrict__ w_tc, const float* __restrict__ b_tc,
    const float* __restrict__ w_in, const float* __restrict__ b_in,
    const float* __restrict__ w_q, const float* __restrict__ b_q,
    const float* __restrict__ w_k, const float* __restrict__ b_k,
    const unsigned int* __restrict__ pmaxk, const float* __restrict__ psum,
    const float* __restrict__ rmax, const float* __restrict__ rsum,
    float* __restrict__ qout, float* __restrict__ kout) {
    __shared__ float pool[512];
    __shared__ float avec[256];
    const int b = blockIdx.x / 7;
    const int idx = blockIdx.x % 7;      // 0..2 = p-side t, 3..6 = f-side f
    const int o = threadIdx.x;
    const bool pside = (idx < 3);
    if (pside) {
        pool[o]       = funkey(pmaxk[(b * 3 + idx) * C_ + o]);
        pool[256 + o] = psum[(b * 3 + idx) * C_ + o] * (1.0f / 4096.0f);
    } else {
        pool[o]       = rmax[b * C_ + o];
        pool[256 + o] = rsum[b * C_ + o] * (1.0f / 4096.0f);
    }
    __syncthreads();
    float s = b_in[o];
    const float* wr = w_in + (size_t)o * 512;
    #pragma unroll 8
    for (int c = 0; c < 512; ++c) s += wr[c] * pool[c];
    float v = silu_f(s);
    float tcin = pside ? past_tc[b * 3 + idx] : fut_tc[b * 4 + (idx - 3)];
    float tc = tanhf(tcin * w_tc[o] + b_tc[o]);
    avec[o] = v + tc;
    __syncthreads();
    if (pside) {
        float s2 = b_k[o];
        const float* wk = w_k + (size_t)o * 256;
        #pragma unroll 8
        for (int c = 0; c < 256; ++c) s2 += wk[c] * avec[c];
        kout[(b * 3 + idx) * C_ + o] = s2;
    } else {
        float s2 = b_q[o];
        const float* wq = w_q + (size_t)o * 256;
        #pragma unroll 8
        for (int c = 0; c < 256; ++c) s2 += wq[c] * avec[c];
        qout[(b * 4 + (idx - 3)) * C_ + o] = s2;
    }
}

// ---------------- K2b: attn_w[b][f][p] = q.k / sqrt(TF) -----------------------
__global__ __launch_bounds__(64) void k2_attnw(const float* __restrict__ qv,
                                               const float* __restrict__ kv,
                                               float* __restrict__ aw) {
    const int i = blockIdx.x;            // 96 = B*TF*TP
    const int b = i / 12, rr = i % 12, f = rr / 3, p = rr % 3;
    const int lane = threadIdx.x;
    const float* qp = qv + (b * 4 + f) * C_;
    const float* kp = kv + (b * 3 + p) * C_;
    float s = 0.0f;
    #pragma unroll
    for (int j = 0; j < 4; ++j) s += qp[lane + 64 * j] * kp[lane + 64 * j];
    #pragma unroll
    for (int m = 1; m < 64; m <<= 1) s += __shfl_xor(s, m);
    if (lane == 0) aw[b * 12 + rr] = s * 0.5f;   // / sqrt(TF=4)
}

// ---------------- K3: out = last + (p_attn/TP) * sum_p aw*(fp3 - fp_p) --------
__global__ __launch_bounds__(256) void k3_out(
    const float* __restrict__ feature, const unsigned short* __restrict__ fp,
    const float* __restrict__ aw, const float* __restrict__ p_attn,
    float* __restrict__ out) {
    const int idx = blockIdx.x;              // 4096 = B * C * 2
    const int b = idx >> 9;
    const int c = (idx >> 1) & 255;
    const int half = idx & 1;
    const int hw = half * 2048 + threadIdx.x * 8;

    float a[12];
    #pragma unroll
    for (int i = 0; i < 12; ++i) a[i] = aw[b * 12 + i];
    const float pa = p_attn[c] * (1.0f / 3.0f);

    const size_t ts = (size_t)C_ * HW_;
    const size_t base = ((size_t)(b * 4) * C_ + c) * HW_ + hw;

    uint4 u0 = *(const uint4*)(fp + base);
    uint4 u1 = *(const uint4*)(fp + base + ts);
    uint4 u2 = *(const uint4*)(fp + base + 2 * ts);
    uint4 u3 = *(const uint4*)(fp + base + 3 * ts);
    float4 l0 = *(const float4*)(feature + base + 3 * ts);
    float4 l1 = *(const float4*)(feature + base + 3 * ts + 4);

    float f0[8], f1[8], f2[8], f3[8];
    dec8(u0, f0); dec8(u1, f1); dec8(u2, f2); dec8(u3, f3);
    float lastv[8] = {l0.x, l0.y, l0.z, l0.w, l1.x, l1.y, l1.z, l1.w};

    float ov[4][8];
    #pragma unroll
    for (int e = 0; e < 8; ++e) {
        float d0 = f3[e] - f0[e];
        float d1 = f3[e] - f1[e];
        float d2 = f3[e] - f2[e];
        #pragma unroll
        for (int f = 0; f < 4; ++f) {
            float at = a[f * 3 + 0] * d0 + a[f * 3 + 1] * d1 + a[f * 3 + 2] * d2;
            ov[f][e] = lastv[e] + at * pa;
        }
    }
    #pragma unroll
    for (int f = 0; f < 4; ++f) {
        size_t ob = ((size_t)(b * 4 + f) * C_ + c) * HW_ + hw;
        *(float4*)(out + ob)     = make_float4(ov[f][0], ov[f][1], ov[f][2], ov[f][3]);
        *(float4*)(out + ob + 4) = make_float4(ov[f][4], ov[f][5], ov[f][6], ov[f][7]);
    }
}

extern "C" void kernel_launch(void* const* d_in, const int* in_sizes, int n_in,
                              void* d_out, int out_size, void* d_ws, size_t ws_size,
                              hipStream_t stream) {
    const float* feature = (const float*)d_in[0];
    const float* past_tc = (const float*)d_in[1];
    const float* fut_tc  = (const float*)d_in[2];
    const float* w_tc    = (const float*)d_in[3];
    const float* b_tc    = (const float*)d_in[4];
    const float* w_in    = (const float*)d_in[5];
    const float* b_in    = (const float*)d_in[6];
    const float* conv_w  = (const float*)d_in[7];
    const float* gamma   = (const float*)d_in[8];
    const float* beta    = (const float*)d_in[9];
    const float* mean    = (const float*)d_in[10];
    const float* var     = (const float*)d_in[11];
    const float* w_q     = (const float*)d_in[12];
    const float* b_q     = (const float*)d_in[13];
    const float* w_k     = (const float*)d_in[14];
    const float* b_k     = (const float*)d_in[15];
    const float* p_attn  = (const float*)d_in[16];

    char* ws = (char*)d_ws;
    unsigned short* fp  = (unsigned short*)(ws + OFF_FP);
    unsigned int* pmaxk = (unsigned int*)(ws + OFF_PMAXK);
    float* psum = (float*)(ws + OFF_PSUM);
    float* rmax = (float*)(ws + OFF_RMAX);
    float* rsum = (float*)(ws + OFF_RSUM);
    float* qout = (float*)(ws + OFF_Q);
    float* kout = (float*)(ws + OFF_K);
    float* aw   = (float*)(ws + OFF_AW);
    // W fragment buffer: workspace if it fits, else scratch in the (not yet
    // written) tail of d_out — k1 finishes reading it before k3 writes out.
    unsigned short* wfrag = (ws_size >= WS_NEED)
        ? (unsigned short*)(ws + OFF_WFRAG)
        : (unsigned short*)((char*)d_out + (size_t)out_size - 131072);

    // zero the fp-pool accumulators (maxkey 0 == below all finite floats; sum 0.0f)
    hipMemsetAsync(ws + OFF_PMAXK, 0, 49152, stream);

    k_wpre<<<256, 256, 0, stream>>>(conv_w, wfrag);
    k0_rawpool<<<B_ * C_, 256, 0, stream>>>(feature, rmax, rsum);
    k1_conv<<<B_ * T1_ * 64, 256, 0, stream>>>(feature, wfrag, gamma, beta, mean, var,
                                               fp, pmaxk, psum);
    k2_vec<<<B_ * 7, 256, 0, stream>>>(past_tc, fut_tc, w_tc, b_tc, w_in, b_in,
                                       w_q, b_q, w_k, b_k, pmaxk, psum, rmax, rsum,
                                       qout, kout);
    k2_attnw<<<B_ * TF_ * TP_, 64, 0, stream>>>(qout, kout, aw);
    k3_out<<<B_ * C_ * 2, 256, 0, stream>>>(feature, fp, aw, p_attn, (float*)d_out);
}